// Round 1
// baseline (772.096 us; speedup 1.0000x reference)
//
#include <hip/hip_runtime.h>
#include <cstddef>

// Winograd-domain strided conv, fp32 correctness-first baseline.
// out[b,o,2i+p,2j+q] = bias[o] + sum_{c,a,d} s_g[p,a] s_g[q,d] * t_g[a,d] * w[o,c,a,d]
// t_g[a,d] = U[d][a] where U = FHT2D( P[perm_g(dy)][perm_g(dx)] ),
// P[dy][dx] = xpad[2i+dy][2j+dx]  (zero pad 1).
// perm: g0 = id, g1 = [1,0,2,3], g2 = [3,1,2,0] (involutions).
// signs s_g[p][a]: g0,g2: {{+,-,+,-},{+,+,-,-}}; g1: {{+,+,+,+},{+,+,-,-}}.

#define IHW 128
#define CIN 64
#define COUT 96
#define NPH 64      // patches per spatial dim
#define TILE 16     // patch tile per block dim (16x16 patches = 256 threads)
#define OCHUNK 8    // output channels per block
#define GSIZE 32    // channels per group

template <int GIDX>
__device__ __forceinline__ constexpr int PERMF(int r) {
  if constexpr (GIDX == 1) { return (r == 0) ? 1 : (r == 1) ? 0 : r; }
  else if constexpr (GIDX == 2) { return (r == 0) ? 3 : (r == 3) ? 0 : r; }
  else { return r; }
}

// true => +1. s_g[p][a].
template <int GIDX>
__device__ __forceinline__ constexpr bool SPOS(int p, int a) {
  if constexpr (GIDX == 1) {
    return (p == 0) ? true : (a < 2);          // {{1,1,1,1},{1,1,-1,-1}}
  } else {
    return (p == 0) ? ((a & 1) == 0) : (a < 2); // {{1,-1,1,-1},{1,1,-1,-1}}
  }
}

template <int GIDX>
__global__ __launch_bounds__(256) void wino_g(const float* __restrict__ x,
                                              const float* __restrict__ w,
                                              const float* __restrict__ bias,
                                              float* __restrict__ out) {
  __shared__ __align__(16) float wlds[OCHUNK * CIN * 16];  // 32 KB

  const int tid = threadIdx.x;
  const int b = blockIdx.y;
  const int chunk = blockIdx.z;                 // 0..3
  const int oc0 = GIDX * GSIZE + chunk * OCHUNK;
  const int ti = (blockIdx.x >> 2) * TILE + (tid >> 4);
  const int tj = (blockIdx.x & 3) * TILE + (tid & 15);
  const int y0 = 2 * ti - 1;
  const int x0 = 2 * tj - 1;

  // stage this chunk's weights: w[oc0 .. oc0+7][64][16] contiguous
  {
    const float4* src = reinterpret_cast<const float4*>(w + (size_t)oc0 * CIN * 16);
    float4* dst = reinterpret_cast<float4*>(wlds);
#pragma unroll
    for (int t = 0; t < (OCHUNK * CIN * 16 / 4) / 256; ++t)
      dst[t * 256 + tid] = src[t * 256 + tid];
  }
  __syncthreads();

  const float* xb = x + (size_t)b * CIN * IHW * IHW;

  float acc[OCHUNK][2][2];
#pragma unroll
  for (int o = 0; o < OCHUNK; ++o) {
    acc[o][0][0] = 0.f; acc[o][0][1] = 0.f; acc[o][1][0] = 0.f; acc[o][1][1] = 0.f;
  }

  for (int c = 0; c < CIN; ++c) {
    const float* xc = xb + (size_t)c * IHW * IHW;

    // load 4x4 patch with zero padding (clamp + mask, branch-free)
    float P[4][4];
#pragma unroll
    for (int dy = 0; dy < 4; ++dy) {
      const int yy = y0 + dy;
      const int cy = min(max(yy, 0), IHW - 1);
      const float ym = ((unsigned)yy < (unsigned)IHW) ? 1.f : 0.f;
#pragma unroll
      for (int dx = 0; dx < 4; ++dx) {
        const int xx = x0 + dx;
        const int cx = min(max(xx, 0), IHW - 1);
        const float m = ((unsigned)xx < (unsigned)IHW) ? ym : 0.f;
        P[dy][dx] = xc[cy * IHW + cx] * m;
      }
    }

    // 2D FHT of permuted patch
    float V[4][4];
#pragma unroll
    for (int r = 0; r < 4; ++r) {
      const float a0 = P[PERMF<GIDX>(r)][PERMF<GIDX>(0)];
      const float a1 = P[PERMF<GIDX>(r)][PERMF<GIDX>(1)];
      const float a2 = P[PERMF<GIDX>(r)][PERMF<GIDX>(2)];
      const float a3 = P[PERMF<GIDX>(r)][PERMF<GIDX>(3)];
      const float b0 = a0 + a1, b1 = a0 - a1, b2 = a2 + a3, b3 = a2 - a3;
      V[r][0] = b0 + b2; V[r][1] = b1 + b3; V[r][2] = b0 - b2; V[r][3] = b1 - b3;
    }
    float U[4][4];
#pragma unroll
    for (int cc = 0; cc < 4; ++cc) {
      const float a0 = V[0][cc], a1 = V[1][cc], a2 = V[2][cc], a3 = V[3][cc];
      const float b0 = a0 + a1, b1 = a0 - a1, b2 = a2 + a3, b3 = a2 - a3;
      U[0][cc] = b0 + b2; U[1][cc] = b1 + b3; U[2][cc] = b0 - b2; U[3][cc] = b1 - b3;
    }

    // accumulate: t[a][d] = U[d][a]; signs compile-time-folded into fma
#pragma unroll
    for (int o = 0; o < OCHUNK; ++o) {
      const float* wr = &wlds[(o * CIN + c) * 16];
#pragma unroll
      for (int a = 0; a < 4; ++a) {
#pragma unroll
        for (int d = 0; d < 4; ++d) {
          const float tv = U[d][a];
          const float wv = wr[a * 4 + d];
          acc[o][0][0] = fmaf((SPOS<GIDX>(0, a) == SPOS<GIDX>(0, d)) ? tv : -tv, wv, acc[o][0][0]);
          acc[o][0][1] = fmaf((SPOS<GIDX>(0, a) == SPOS<GIDX>(1, d)) ? tv : -tv, wv, acc[o][0][1]);
          acc[o][1][0] = fmaf((SPOS<GIDX>(1, a) == SPOS<GIDX>(0, d)) ? tv : -tv, wv, acc[o][1][0]);
          acc[o][1][1] = fmaf((SPOS<GIDX>(1, a) == SPOS<GIDX>(1, d)) ? tv : -tv, wv, acc[o][1][1]);
        }
      }
    }
  }

  // epilogue: bias + store 2x2 per (patch, oc) as two float2
#pragma unroll
  for (int o = 0; o < OCHUNK; ++o) {
    const int oc = oc0 + o;
    const float bv = bias[oc];
#pragma unroll
    for (int p = 0; p < 2; ++p) {
      float2 v = make_float2(acc[o][p][0] + bv, acc[o][p][1] + bv);
      float* dst = out + (((size_t)b * COUT + oc) * IHW + (2 * ti + p)) * IHW + 2 * tj;
      *reinterpret_cast<float2*>(dst) = v;
    }
  }
}

extern "C" void kernel_launch(void* const* d_in, const int* in_sizes, int n_in,
                              void* d_out, int out_size, void* d_ws, size_t ws_size,
                              hipStream_t stream) {
  const float* x = (const float*)d_in[0];
  const float* w = (const float*)d_in[1];
  const float* bias = (const float*)d_in[2];
  float* out = (float*)d_out;

  dim3 grid(16, 16, 4);  // 16 spatial tiles, 16 batches, 4 oc-chunks
  dim3 block(256);
  hipLaunchKernelGGL((wino_g<0>), grid, block, 0, stream, x, w, bias, out);
  hipLaunchKernelGGL((wino_g<1>), grid, block, 0, stream, x, w, bias, out);
  hipLaunchKernelGGL((wino_g<2>), grid, block, 0, stream, x, w, bias, out);
}

// Round 2
// 335.647 us; speedup vs baseline: 2.3003x; 2.3003x over previous
//
#include <hip/hip_runtime.h>
#include <cstddef>
#include <cstdint>

// Direct-conv reformulation of the Winograd reference:
// out[b,o,2i+p,2j+q] = bias[o] + sum_{c,y,x} xpad[b,c,2i-1+y,2j-1+x] * Keff[o,c,p,q,y,x]
// Keff[o,c,p,q,y,x] = sum_{a,d} s_g[p,a] s_g[q,d] H[a,perm_g(x)] H[d,perm_g(y)] w[o,c,a,d]
// (signs/perms validated by the passing round-0 kernel).
// Implicit GEMM: M = 65536 patches, N = 384 (o*4+p*2+q), K = 1024 (c*16+y*4+x), bf16 MFMA.

#define IHW 128
#define CIN 64
#define COUT 96

typedef __attribute__((ext_vector_type(8))) short short8_t;  // bf16x8 operand
typedef __attribute__((ext_vector_type(4))) float floatx4;   // f32 accum

__device__ __forceinline__ short bf16r(float f) {  // RNE fp32->bf16
  uint32_t u = __float_as_uint(f);
  uint32_t r = (u + 0x7FFFu + ((u >> 16) & 1u)) >> 16;
  return (short)r;
}

// ---------------- Keff precompute: one thread per (o,c) ----------------
__global__ void keff_kernel(const float* __restrict__ w, short* __restrict__ keff) {
  int idx = blockIdx.x * 256 + threadIdx.x;
  if (idx >= COUT * CIN) return;
  int o = idx / CIN, c = idx % CIN;
  int g = o / 32;

  int perm[4] = {0, 1, 2, 3};
  if (g == 1) { perm[0] = 1; perm[1] = 0; }
  else if (g == 2) { perm[0] = 3; perm[3] = 0; }

  const float H[4][4] = {{1,1,1,1},{1,-1,1,-1},{1,1,-1,-1},{1,-1,-1,1}};
  float S[2][4];
#pragma unroll
  for (int p = 0; p < 2; ++p)
#pragma unroll
    for (int a = 0; a < 4; ++a) {
      bool pos = (g == 1) ? ((p == 0) ? true : (a < 2))
                          : ((p == 0) ? ((a & 1) == 0) : (a < 2));
      S[p][a] = pos ? 1.f : -1.f;
    }

  float wv[4][4];
#pragma unroll
  for (int a = 0; a < 4; ++a)
#pragma unroll
    for (int d = 0; d < 4; ++d) wv[a][d] = w[(o * CIN + c) * 16 + a * 4 + d];

  for (int p = 0; p < 2; ++p)
    for (int q = 0; q < 2; ++q) {
      int n = o * 4 + p * 2 + q;
      for (int y = 0; y < 4; ++y)
        for (int xx = 0; xx < 4; ++xx) {
          float s = 0.f;
#pragma unroll
          for (int a = 0; a < 4; ++a) {
            float ea = S[p][a] * H[a][perm[xx]];
#pragma unroll
            for (int d = 0; d < 4; ++d) s += ea * S[q][d] * H[d][perm[y]] * wv[a][d];
          }
          keff[n * 1024 + c * 16 + y * 4 + xx] = bf16r(s);
        }
    }
}

// ---------------- main conv kernel ----------------
// block: 256 threads = 4 waves (2 M-halves x 2 N-halves)
// block tile: M = 128 patches (2 i-rows x 64 j), N = 192 features (blockIdx.y picks half)
// K-loop: 8 chunks of 8 channels; LDS holds fp32 image tile [8c][6 rows][pitch 136 dwords]
#define PITCH 136
#define TROWS 6

__global__ __launch_bounds__(256) void conv_mfma(const float* __restrict__ x,
                                                 const short* __restrict__ keff,
                                                 const float* __restrict__ bias,
                                                 float* __restrict__ out) {
  __shared__ float tile[8 * TROWS * PITCH];  // 26112 B

  const int tid = threadIdx.x;
  const int lane = tid & 63;
  const int wid = tid >> 6;
  const int wavem = wid >> 1;  // i-row within block (0..1)
  const int wn = wid & 1;      // n-half (96 features each)
  const int l15 = lane & 15;
  const int l4 = lane >> 4;

  const int bx = blockIdx.x;   // 0..511
  const int b = bx >> 5;
  const int ib = bx & 31;      // i-pair
  const int nblk = blockIdx.y; // 0..1

  floatx4 acc[4][6];
#pragma unroll
  for (int i = 0; i < 4; ++i)
#pragma unroll
    for (int j = 0; j < 6; ++j) acc[i][j] = (floatx4){0.f, 0.f, 0.f, 0.f};

  // per-lane Keff base: n = nblk*192 + wn*96 + nf*16 + l15 ; k = l4*8 + ...
  const short* kbase = keff + ((size_t)(nblk * 192 + wn * 96 + l15)) * 1024 + l4 * 8;

  float biasr[6];
#pragma unroll
  for (int nf = 0; nf < 6; ++nf) biasr[nf] = bias[nblk * 48 + wn * 24 + nf * 4 + l4];

  const int gy0 = ib * 4 - 1;  // global y for tile row t=0
  const float* xb = x + (size_t)b * CIN * IHW * IHW;

  for (int ck = 0; ck < 8; ++ck) {
    __syncthreads();  // protect previous chunk's reads
    // stage interior: 8c * 6t * 128 = 6144 dwords, 24 per thread, fully coalesced
#pragma unroll
    for (int it = 0; it < 24; ++it) {
      int f = tid + it * 256;
      int gx = f & 127;
      int rr = f >> 7;  // c_loc*6 + t
      int cc = rr / TROWS, t = rr - cc * TROWS;
      int gy = gy0 + t;
      float v = 0.f;
      if ((unsigned)gy < (unsigned)IHW)
        v = xb[((size_t)(ck * 8 + cc) * IHW + gy) * IHW + gx];
      tile[rr * PITCH + 1 + gx] = v;
    }
    // padding columns (gx = -1 -> col 0, gx = 128 -> col 129)
    if (tid < 96) {
      int rr = tid >> 1;
      int col = (tid & 1) ? 129 : 0;
      tile[rr * PITCH + col] = 0.f;
    }
    __syncthreads();

#pragma unroll
    for (int kk = 0; kk < 4; ++kk) {
      const int kof = ck * 128 + kk * 32;
      short8_t af[6];
#pragma unroll
      for (int nf = 0; nf < 6; ++nf)
        af[nf] = *reinterpret_cast<const short8_t*>(kbase + nf * 16 * 1024 + kof);

      const int c_loc = 2 * kk + (l4 >> 1);
      const int y0 = (l4 & 1) * 2;
      const int rowb = (c_loc * TROWS + 2 * wavem + y0) * PITCH;

#pragma unroll
      for (int mf = 0; mf < 4; ++mf) {
        const int col = rowb + 2 * (mf * 16 + l15);
        float2 v0 = *reinterpret_cast<const float2*>(&tile[col]);
        float2 v1 = *reinterpret_cast<const float2*>(&tile[col + 2]);
        float2 v2 = *reinterpret_cast<const float2*>(&tile[col + PITCH]);
        float2 v3 = *reinterpret_cast<const float2*>(&tile[col + PITCH + 2]);
        short8_t bfrag;
        bfrag[0] = bf16r(v0.x); bfrag[1] = bf16r(v0.y);
        bfrag[2] = bf16r(v1.x); bfrag[3] = bf16r(v1.y);
        bfrag[4] = bf16r(v2.x); bfrag[5] = bf16r(v2.y);
        bfrag[6] = bf16r(v3.x); bfrag[7] = bf16r(v3.y);
#pragma unroll
        for (int nf = 0; nf < 6; ++nf)
          acc[mf][nf] = __builtin_amdgcn_mfma_f32_16x16x32_bf16(af[nf], bfrag,
                                                                acc[mf][nf], 0, 0, 0);
      }
    }
  }

  // epilogue: D row = n = base + l4*4 + r (pq = r), D col = patch j = mf*16+l15
  const int i_row = ib * 2 + wavem;
  const int orow0 = 2 * i_row;
#pragma unroll
  for (int nf = 0; nf < 6; ++nf) {
    const int o = nblk * 48 + wn * 24 + nf * 4 + l4;
    const float bv = biasr[nf];
    float* obase = out + ((size_t)(b * COUT + o) * IHW + orow0) * IHW;
#pragma unroll
    for (int mf = 0; mf < 4; ++mf) {
      const int col = 2 * (mf * 16 + l15);
      float2 s0 = make_float2(acc[mf][nf][0] + bv, acc[mf][nf][1] + bv);
      float2 s1 = make_float2(acc[mf][nf][2] + bv, acc[mf][nf][3] + bv);
      *reinterpret_cast<float2*>(obase + col) = s0;
      *reinterpret_cast<float2*>(obase + IHW + col) = s1;
    }
  }
}

extern "C" void kernel_launch(void* const* d_in, const int* in_sizes, int n_in,
                              void* d_out, int out_size, void* d_ws, size_t ws_size,
                              hipStream_t stream) {
  const float* x = (const float*)d_in[0];
  const float* w = (const float*)d_in[1];
  const float* bias = (const float*)d_in[2];
  float* out = (float*)d_out;
  short* keff = (short*)d_ws;  // 384*1024*2 B = 786 KB

  hipLaunchKernelGGL(keff_kernel, dim3(24), dim3(256), 0, stream, w, keff);
  hipLaunchKernelGGL(conv_mfma, dim3(512, 2), dim3(256), 0, stream, x, keff, bias, out);
}

// Round 3
// 123.444 us; speedup vs baseline: 6.2546x; 2.7190x over previous
//
#include <hip/hip_runtime.h>
#include <hip/hip_bf16.h>
#include <cstddef>
#include <cstdint>

// Direct-conv reformulation of the Winograd reference (validated r1/r2):
// out[b,o,2i+p,2j+q] = bias[o] + sum_{c,y,x} xpad[b,c,2i-1+y,2j-1+x] * Keff[o,c,p,q,y,x]
// Implicit GEMM: M=65536 patches, N=384 (o*4+p*2+q), K=1024 (c*16+y*4+x), bf16 MFMA.
// Round 3: double-buffered global_load_lds staging (counted vmcnt, raw barriers)
//          + A-frag (Keff) one-step software pipeline + hw bf16 cvt.

#define IHW 128
#define CIN 64
#define COUT 96

typedef __attribute__((ext_vector_type(8))) short short8_t;  // bf16x8 operand
typedef __attribute__((ext_vector_type(4))) float floatx4;   // f32 accum

__device__ __forceinline__ short bf16r(float f) {  // RNE fp32->bf16 (keff precompute)
  uint32_t u = __float_as_uint(f);
  uint32_t r = (u + 0x7FFFu + ((u >> 16) & 1u)) >> 16;
  return (short)r;
}

__device__ __forceinline__ short cvb(float f) {  // hw cvt path (v_cvt_pk-fusable)
  union { __hip_bfloat16 h; short s; } u;
  u.h = __float2bfloat16(f);
  return u.s;
}

// ---------------- Keff precompute + zero-page init ----------------
__global__ void keff_kernel(const float* __restrict__ w, short* __restrict__ keff,
                            float* __restrict__ zp) {
  if (blockIdx.x == 0) zp[threadIdx.x] = 0.f;  // 1 KB zero page for OOB staging lanes
  int idx = blockIdx.x * 256 + threadIdx.x;
  if (idx >= COUT * CIN) return;
  int o = idx / CIN, c = idx % CIN;
  int g = o / 32;

  int perm[4] = {0, 1, 2, 3};
  if (g == 1) { perm[0] = 1; perm[1] = 0; }
  else if (g == 2) { perm[0] = 3; perm[3] = 0; }

  const float H[4][4] = {{1,1,1,1},{1,-1,1,-1},{1,1,-1,-1},{1,-1,-1,1}};
  float S[2][4];
#pragma unroll
  for (int p = 0; p < 2; ++p)
#pragma unroll
    for (int a = 0; a < 4; ++a) {
      bool pos = (g == 1) ? ((p == 0) ? true : (a < 2))
                          : ((p == 0) ? ((a & 1) == 0) : (a < 2));
      S[p][a] = pos ? 1.f : -1.f;
    }

  float wv[4][4];
#pragma unroll
  for (int a = 0; a < 4; ++a)
#pragma unroll
    for (int d = 0; d < 4; ++d) wv[a][d] = w[(o * CIN + c) * 16 + a * 4 + d];

  for (int p = 0; p < 2; ++p)
    for (int q = 0; q < 2; ++q) {
      int n = o * 4 + p * 2 + q;
      for (int y = 0; y < 4; ++y)
        for (int xx = 0; xx < 4; ++xx) {
          float s = 0.f;
#pragma unroll
          for (int a = 0; a < 4; ++a) {
            float ea = S[p][a] * H[a][perm[xx]];
#pragma unroll
            for (int d = 0; d < 4; ++d) s += ea * S[q][d] * H[d][perm[y]] * wv[a][d];
          }
          keff[n * 1024 + c * 16 + y * 4 + xx] = bf16r(s);
        }
    }
}

// ---------------- main conv kernel ----------------
// block: 256 threads = 4 waves (2 M x 2 N). Block tile M=128 patches, N=192.
// LDS: double-buffered fp32 x-tile, rows [rr=c_loc*6+t][gx 0..127], linear (gload_lds).
#define NROWS 48
#define BUFDW (NROWS * 128)  // 6144 dwords per buffer
#define GUARD 16

__global__ __launch_bounds__(256) void conv_mfma(const float* __restrict__ x,
                                                 const short* __restrict__ keff,
                                                 const float* __restrict__ bias,
                                                 const float* __restrict__ zp,
                                                 float* __restrict__ out) {
  __shared__ float lds[GUARD + 2 * BUFDW + GUARD];  // 49280 B

  const int tid = threadIdx.x;
  const int lane = tid & 63;
  const int wid = tid >> 6;
  const int wavem = wid >> 1;
  const int wn = wid & 1;
  const int l15 = lane & 15;
  const int l4 = lane >> 4;

  const int bx = blockIdx.x;
  const int b = bx >> 5;
  const int ib = bx & 31;
  const int nblk = blockIdx.y;
  const int gy0 = ib * 4 - 1;

  const float* xb = x + (size_t)b * CIN * IHW * IHW;

  // ---- staging descriptors: pair pr = wid*6+s covers rows (2h,2h+1) of c_loc ----
  const float* sbase[6];
  bool svalid[6];
#pragma unroll
  for (int s = 0; s < 6; ++s) {
    const int pr = wid * 6 + s;
    const int c_loc = pr / 3;
    const int h = pr % 3;
    const int trow = 2 * h + (lane >> 5);
    const int gy = gy0 + trow;
    const bool v = (unsigned)gy < (unsigned)IHW;
    sbase[s] = xb + ((size_t)c_loc * IHW + (v ? gy : 0)) * IHW + (lane & 31) * 4;
    svalid[s] = v;
  }

#define STAGE(bufsel, ck)                                                          \
  {                                                                                \
    _Pragma("unroll") for (int s = 0; s < 6; ++s) {                                \
      const float* src =                                                           \
          svalid[s] ? sbase[s] + (size_t)(ck) * (8 * IHW * IHW) : zp;              \
      __builtin_amdgcn_global_load_lds(                                            \
          (const __attribute__((address_space(1))) void*)src,                      \
          (__attribute__((address_space(3))) void*)                                \
              &lds[GUARD + (bufsel) * BUFDW + (wid * 6 + s) * 256],                \
          16, 0, 0);                                                               \
    }                                                                              \
  }

  floatx4 acc[4][6];
#pragma unroll
  for (int i = 0; i < 4; ++i)
#pragma unroll
    for (int j = 0; j < 6; ++j) acc[i][j] = (floatx4){0.f, 0.f, 0.f, 0.f};

  const short* kbase = keff + ((size_t)(nblk * 192 + wn * 96 + l15)) * 1024 + l4 * 8;

  float biasr[6];
#pragma unroll
  for (int nf = 0; nf < 6; ++nf) biasr[nf] = bias[nblk * 48 + wn * 24 + nf * 4 + l4];

  // prologue: stage chunk 0, prime A-frag pipeline
  STAGE(0, 0);
  short8_t afc[6], afn[6];
#pragma unroll
  for (int nf = 0; nf < 6; ++nf)
    afc[nf] = *reinterpret_cast<const short8_t*>(kbase + nf * 16 * 1024);

  for (int ck = 0; ck < 8; ++ck) {
    if (ck < 7) STAGE((ck + 1) & 1, ck + 1);
    asm volatile("s_waitcnt vmcnt(6)" ::: "memory");
    __builtin_amdgcn_s_barrier();
    __builtin_amdgcn_sched_barrier(0);

    const int bb = GUARD + (ck & 1) * BUFDW;
#pragma unroll
    for (int kk = 0; kk < 4; ++kk) {
      const int step = ck * 4 + kk;
      const int nstep = (step + 1) & 31;
#pragma unroll
      for (int nf = 0; nf < 6; ++nf)
        afn[nf] = *reinterpret_cast<const short8_t*>(kbase + nf * 16 * 1024 + nstep * 32);

      const int c_loc = 2 * kk + (l4 >> 1);
      const int row = c_loc * 6 + 2 * wavem + ((l4 & 1) * 2);
      const int rb = bb + row * 128;

#pragma unroll
      for (int mf = 0; mf < 4; ++mf) {
        const int cb = rb + 2 * (mf * 16 + l15);
        float f0 = lds[cb - 1], f1 = lds[cb], f2 = lds[cb + 1], f3 = lds[cb + 2];
        float g0 = lds[cb + 127], g1 = lds[cb + 128], g2 = lds[cb + 129], g3 = lds[cb + 130];
        if (mf == 0 && l15 == 0) { f0 = 0.f; g0 = 0.f; }   // gx = -1
        if (mf == 3 && l15 == 15) { f3 = 0.f; g3 = 0.f; }  // gx = 128
        short8_t bfrag;
        bfrag[0] = cvb(f0); bfrag[1] = cvb(f1); bfrag[2] = cvb(f2); bfrag[3] = cvb(f3);
        bfrag[4] = cvb(g0); bfrag[5] = cvb(g1); bfrag[6] = cvb(g2); bfrag[7] = cvb(g3);
#pragma unroll
        for (int nf = 0; nf < 6; ++nf)
          acc[mf][nf] = __builtin_amdgcn_mfma_f32_16x16x32_bf16(afc[nf], bfrag,
                                                                acc[mf][nf], 0, 0, 0);
      }
#pragma unroll
      for (int nf = 0; nf < 6; ++nf) afc[nf] = afn[nf];
    }
    __builtin_amdgcn_s_barrier();
  }

  // epilogue (unchanged from validated r2): D row = n, D col = patch j
  const int i_row = ib * 2 + wavem;
  const int orow0 = 2 * i_row;
#pragma unroll
  for (int nf = 0; nf < 6; ++nf) {
    const int o = nblk * 48 + wn * 24 + nf * 4 + l4;
    const float bv = biasr[nf];
    float* obase = out + ((size_t)(b * COUT + o) * IHW + orow0) * IHW;
#pragma unroll
    for (int mf = 0; mf < 4; ++mf) {
      const int col = 2 * (mf * 16 + l15);
      float2 s0 = make_float2(acc[mf][nf][0] + bv, acc[mf][nf][1] + bv);
      float2 s1 = make_float2(acc[mf][nf][2] + bv, acc[mf][nf][3] + bv);
      *reinterpret_cast<float2*>(obase + col) = s0;
      *reinterpret_cast<float2*>(obase + IHW + col) = s1;
    }
  }
#undef STAGE
}

extern "C" void kernel_launch(void* const* d_in, const int* in_sizes, int n_in,
                              void* d_out, int out_size, void* d_ws, size_t ws_size,
                              hipStream_t stream) {
  const float* x = (const float*)d_in[0];
  const float* w = (const float*)d_in[1];
  const float* bias = (const float*)d_in[2];
  float* out = (float*)d_out;
  short* keff = (short*)d_ws;                              // 786432 B
  float* zp = (float*)((char*)d_ws + 786432);              // 1 KB zero page

  hipLaunchKernelGGL(keff_kernel, dim3(24), dim3(256), 0, stream, w, keff, zp);
  hipLaunchKernelGGL(conv_mfma, dim3(512, 2), dim3(256), 0, stream, x, keff, bias, zp, out);
}

// Round 4
// 119.270 us; speedup vs baseline: 6.4735x; 1.0350x over previous
//
#include <hip/hip_runtime.h>
#include <hip/hip_bf16.h>
#include <cstddef>
#include <cstdint>

// Direct-conv reformulation of the Winograd reference (validated r1-r3):
// out[b,o,2i+p,2j+q] = bias[o] + sum_{c,y,x} xpad[b,c,2i-1+y,2j-1+x] * Keff[o,c,p,q,y,x]
// Implicit GEMM: M=65536 patches, N=384 (o*4+p*2+q), K=1024 (c*16+y*4+x), bf16 MFMA.
// Round 4: pair-gap LDS pitch (257 dwords/row-pair; 257 % 32 == 1 -> 2-way max, free)
//          + XCD-aware (tile, nblk) pairing so both n-halves share one XCD's L2.

#define IHW 128
#define CIN 64
#define COUT 96

typedef __attribute__((ext_vector_type(8))) short short8_t;  // bf16x8 operand
typedef __attribute__((ext_vector_type(4))) float floatx4;   // f32 accum

__device__ __forceinline__ short bf16r(float f) {  // RNE fp32->bf16 (keff precompute)
  uint32_t u = __float_as_uint(f);
  uint32_t r = (u + 0x7FFFu + ((u >> 16) & 1u)) >> 16;
  return (short)r;
}

__device__ __forceinline__ short cvb(float f) {  // hw cvt path (v_cvt_pk-fusable)
  union { __hip_bfloat16 h; short s; } u;
  u.h = __float2bfloat16(f);
  return u.s;
}

// ---------------- Keff precompute + zero-page init ----------------
__global__ void keff_kernel(const float* __restrict__ w, short* __restrict__ keff,
                            float* __restrict__ zp) {
  if (blockIdx.x == 0) zp[threadIdx.x] = 0.f;  // 1 KB zero page for OOB staging lanes
  int idx = blockIdx.x * 256 + threadIdx.x;
  if (idx >= COUT * CIN) return;
  int o = idx / CIN, c = idx % CIN;
  int g = o / 32;

  int perm[4] = {0, 1, 2, 3};
  if (g == 1) { perm[0] = 1; perm[1] = 0; }
  else if (g == 2) { perm[0] = 3; perm[3] = 0; }

  const float H[4][4] = {{1,1,1,1},{1,-1,1,-1},{1,1,-1,-1},{1,-1,-1,1}};
  float S[2][4];
#pragma unroll
  for (int p = 0; p < 2; ++p)
#pragma unroll
    for (int a = 0; a < 4; ++a) {
      bool pos = (g == 1) ? ((p == 0) ? true : (a < 2))
                          : ((p == 0) ? ((a & 1) == 0) : (a < 2));
      S[p][a] = pos ? 1.f : -1.f;
    }

  float wv[4][4];
#pragma unroll
  for (int a = 0; a < 4; ++a)
#pragma unroll
    for (int d = 0; d < 4; ++d) wv[a][d] = w[(o * CIN + c) * 16 + a * 4 + d];

  for (int p = 0; p < 2; ++p)
    for (int q = 0; q < 2; ++q) {
      int n = o * 4 + p * 2 + q;
      for (int y = 0; y < 4; ++y)
        for (int xx = 0; xx < 4; ++xx) {
          float s = 0.f;
#pragma unroll
          for (int a = 0; a < 4; ++a) {
            float ea = S[p][a] * H[a][perm[xx]];
#pragma unroll
            for (int d = 0; d < 4; ++d) s += ea * S[q][d] * H[d][perm[y]] * wv[a][d];
          }
          keff[n * 1024 + c * 16 + y * 4 + xx] = bf16r(s);
        }
    }
}

// ---------------- main conv kernel ----------------
// block: 256 threads = 4 waves (2 M x 2 N). Block tile M=128 patches, N=192.
// LDS: double-buffered fp32 x-tile; row-pair p (2 rows x 128 dwords, 1 KB stage unit)
// lives at dword offset p*257 -> pair shift of 1 bank -> l4 groups {0,1,3,4} split
// even/odd bank parity -> max 2-way (free).
#define PPITCH 257
#define NPAIRS 24
#define BUFDW (NPAIRS * PPITCH)  // 6168 dwords per buffer
#define GUARD 16

__global__ __launch_bounds__(256) void conv_mfma(const float* __restrict__ x,
                                                 const short* __restrict__ keff,
                                                 const float* __restrict__ bias,
                                                 const float* __restrict__ zp,
                                                 float* __restrict__ out) {
  __shared__ float lds[GUARD + 2 * BUFDW + GUARD];  // 49,472 B -> 3 blocks/CU

  const int tid = threadIdx.x;
  const int lane = tid & 63;
  const int wid = tid >> 6;
  const int wavem = wid >> 1;
  const int wn = wid & 1;
  const int l15 = lane & 15;
  const int l4 = lane >> 4;

  // XCD-aware decomposition: both nblk of a tile land on the same XCD (id & 7).
  const int hw = blockIdx.x;          // 0..1023
  const int xcd = hw & 7;
  const int j = hw >> 3;              // 0..127
  const int tile = (xcd << 6) | (j >> 1);  // 0..511
  const int nblk = j & 1;
  const int b = tile >> 5;
  const int ib = tile & 31;
  const int gy0 = ib * 4 - 1;

  const float* xb = x + (size_t)b * CIN * IHW * IHW;

  // ---- staging descriptors: pair pr = wid*6+s covers rows (2h,2h+1) of c_loc ----
  const float* sbase[6];
  bool svalid[6];
#pragma unroll
  for (int s = 0; s < 6; ++s) {
    const int pr = wid * 6 + s;
    const int c_loc = pr / 3;
    const int h = pr % 3;
    const int trow = 2 * h + (lane >> 5);
    const int gy = gy0 + trow;
    const bool v = (unsigned)gy < (unsigned)IHW;
    sbase[s] = xb + ((size_t)c_loc * IHW + (v ? gy : 0)) * IHW + (lane & 31) * 4;
    svalid[s] = v;
  }

#define STAGE(bufsel, ck)                                                          \
  {                                                                                \
    _Pragma("unroll") for (int s = 0; s < 6; ++s) {                                \
      const float* src =                                                           \
          svalid[s] ? sbase[s] + (size_t)(ck) * (8 * IHW * IHW) : zp;              \
      __builtin_amdgcn_global_load_lds(                                            \
          (const __attribute__((address_space(1))) void*)src,                      \
          (__attribute__((address_space(3))) void*)                                \
              &lds[GUARD + (bufsel) * BUFDW + (wid * 6 + s) * PPITCH],             \
          16, 0, 0);                                                               \
    }                                                                              \
  }

  floatx4 acc[4][6];
#pragma unroll
  for (int i = 0; i < 4; ++i)
#pragma unroll
    for (int j2 = 0; j2 < 6; ++j2) acc[i][j2] = (floatx4){0.f, 0.f, 0.f, 0.f};

  const short* kbase = keff + ((size_t)(nblk * 192 + wn * 96 + l15)) * 1024 + l4 * 8;

  float biasr[6];
#pragma unroll
  for (int nf = 0; nf < 6; ++nf) biasr[nf] = bias[nblk * 48 + wn * 24 + nf * 4 + l4];

  // prologue: stage chunk 0, prime A-frag pipeline
  STAGE(0, 0);
  short8_t afc[6], afn[6];
#pragma unroll
  for (int nf = 0; nf < 6; ++nf)
    afc[nf] = *reinterpret_cast<const short8_t*>(kbase + nf * 16 * 1024);

  for (int ck = 0; ck < 8; ++ck) {
    if (ck < 7) STAGE((ck + 1) & 1, ck + 1);
    asm volatile("s_waitcnt vmcnt(6)" ::: "memory");
    __builtin_amdgcn_s_barrier();
    __builtin_amdgcn_sched_barrier(0);

    const int bb = GUARD + (ck & 1) * BUFDW;
#pragma unroll
    for (int kk = 0; kk < 4; ++kk) {
      const int step = ck * 4 + kk;
      const int nstep = (step + 1) & 31;
#pragma unroll
      for (int nf = 0; nf < 6; ++nf)
        afn[nf] = *reinterpret_cast<const short8_t*>(kbase + nf * 16 * 1024 + nstep * 32);

      // pair index: row = c_loc*6 + 2*wavem + 2*(l4&1)  (always even)
      const int p = (2 * kk + (l4 >> 1)) * 3 + wavem + (l4 & 1);
      const int rb = bb + p * PPITCH;

#pragma unroll
      for (int mf = 0; mf < 4; ++mf) {
        const int cb = rb + 2 * (mf * 16 + l15);
        float f0 = lds[cb - 1], f1 = lds[cb], f2 = lds[cb + 1], f3 = lds[cb + 2];
        float g0 = lds[cb + 127], g1 = lds[cb + 128], g2 = lds[cb + 129], g3 = lds[cb + 130];
        if (mf == 0 && l15 == 0) { f0 = 0.f; g0 = 0.f; }   // gx = -1
        if (mf == 3 && l15 == 15) { f3 = 0.f; g3 = 0.f; }  // gx = 128
        short8_t bfrag;
        bfrag[0] = cvb(f0); bfrag[1] = cvb(f1); bfrag[2] = cvb(f2); bfrag[3] = cvb(f3);
        bfrag[4] = cvb(g0); bfrag[5] = cvb(g1); bfrag[6] = cvb(g2); bfrag[7] = cvb(g3);
#pragma unroll
        for (int nf = 0; nf < 6; ++nf)
          acc[mf][nf] = __builtin_amdgcn_mfma_f32_16x16x32_bf16(afc[nf], bfrag,
                                                                acc[mf][nf], 0, 0, 0);
      }
#pragma unroll
      for (int nf = 0; nf < 6; ++nf) afc[nf] = afn[nf];
    }
    __builtin_amdgcn_s_barrier();
  }

  // epilogue (unchanged, validated r2): D row = n, D col = patch j
  const int i_row = ib * 2 + wavem;
  const int orow0 = 2 * i_row;
#pragma unroll
  for (int nf = 0; nf < 6; ++nf) {
    const int o = nblk * 48 + wn * 24 + nf * 4 + l4;
    const float bv = biasr[nf];
    float* obase = out + ((size_t)(b * COUT + o) * IHW + orow0) * IHW;
#pragma unroll
    for (int mf = 0; mf < 4; ++mf) {
      const int col = 2 * (mf * 16 + l15);
      float2 s0 = make_float2(acc[mf][nf][0] + bv, acc[mf][nf][1] + bv);
      float2 s1 = make_float2(acc[mf][nf][2] + bv, acc[mf][nf][3] + bv);
      *reinterpret_cast<float2*>(obase + col) = s0;
      *reinterpret_cast<float2*>(obase + IHW + col) = s1;
    }
  }
#undef STAGE
}

extern "C" void kernel_launch(void* const* d_in, const int* in_sizes, int n_in,
                              void* d_out, int out_size, void* d_ws, size_t ws_size,
                              hipStream_t stream) {
  const float* x = (const float*)d_in[0];
  const float* w = (const float*)d_in[1];
  const float* bias = (const float*)d_in[2];
  float* out = (float*)d_out;
  short* keff = (short*)d_ws;                              // 786432 B
  float* zp = (float*)((char*)d_ws + 786432);              // 1 KB zero page

  hipLaunchKernelGGL(keff_kernel, dim3(24), dim3(256), 0, stream, w, keff, zp);
  hipLaunchKernelGGL(conv_mfma, dim3(1024), dim3(256), 0, stream, x, keff, bias, zp, out);
}